// Round 7
// baseline (260.492 us; speedup 1.0000x reference)
//
#include <hip/hip_runtime.h>

// VectorCollapseEngine R8: R7 + load-batching (latency de-exposure).
// R7 counters: fused=85.5us, VALUBusy=19%, HBM=30% -> both pipes idle, and
// harness fills prove 6.65 TB/s is reachable at 9.5% occupancy. Diagnosis:
// pass-1 interleaved {load hv[j]; ds_read anchors; FMAs consuming hv[j]}
// forces a waitcnt per iteration -> each wave exposes ~16x600cy of latency.
// R8: (1) pass 1 issues ALL 16 h-loads back-to-back (one wait, not 16);
//     (2) anchor-dot and pass-2 loops read LDS in chunks of 4 j's
//         (12 ds_read_b128 in flight before consumption);
//     (3) __launch_bounds__(512,4) -> 128-VGPR cap so the batch fits
//         without spills (est ~110 VGPR, still 2 blocks/CU).
// Structure otherwise R7: wave-per-row, LDS-staged anchors (48KB, one
// barrier), butterfly reduce, division-free recurrence, h in VGPRs.
// Floor ~32us (66MB L3-miss fetch + 137MB write).

constexpr int DIM = 4096;
constexpr int BATCH = 8192;
constexpr int NLAYERS = 6;
constexpr int TPB = 512;                  // 8 waves per block
constexpr int WPB = TPB / 64;             // waves per block = 8
constexpr int GRID = BATCH / WPB;         // 1024 blocks, 1 row per wave
constexpr int FPW = DIM / (64 * 4);       // float4 chunks per lane = 16
constexpr int CHUNK = 4;                  // j's per LDS-read batch
constexpr int GTPB = 256;                 // gram kernel block size

constexpr size_t HOUT = (size_t)BATCH * DIM;            // h_final elems
constexpr size_t TRACE = (size_t)NLAYERS * BATCH * 3;   // per-trace elems
constexpr size_t OFF_ALIGN = HOUT;
constexpr size_t OFF_DIV   = HOUT + TRACE;
constexpr size_t OFF_TENS  = HOUT + 2 * TRACE;

// g_gram: [rn0, rn1, rn2, G00, G11, G22, G01, G02, G12]  (rn = 1/|anchor|)
__device__ float g_gram[12];

__device__ __forceinline__ float frcp(float x) { return __builtin_amdgcn_rcpf(x); }
__device__ __forceinline__ float frsq(float x) { return __builtin_amdgcn_rsqf(x); }
__device__ __forceinline__ float fsq(float x)  { return __builtin_amdgcn_sqrtf(x); }

__device__ __forceinline__ float wave_red(float v) {   // lane-0 sum (setup only)
#pragma unroll
  for (int off = 32; off > 0; off >>= 1) v += __shfl_down(v, off, 64);
  return v;
}

__device__ __forceinline__ float wave_allred(float v) { // all lanes get sum
#pragma unroll
  for (int off = 32; off > 0; off >>= 1) v += __shfl_xor(v, off, 64);
  return v;
}

// ---- setup: anchor Gram / inverse norms (1 block; precise math, cold) ----
__global__ __launch_bounds__(GTPB) void gram_kernel(
    const float* __restrict__ an0, const float* __restrict__ an1,
    const float* __restrict__ an2) {
  const int tid = threadIdx.x;
  float r[6];
#pragma unroll
  for (int i = 0; i < 6; ++i) r[i] = 0.f;
#pragma unroll
  for (int j = 0; j < DIM / (GTPB * 4); ++j) {
    const int idx = (tid + j * GTPB) * 4;
    const float4 x = *(const float4*)(an0 + idx);
    const float4 y = *(const float4*)(an1 + idx);
    const float4 z = *(const float4*)(an2 + idx);
    r[0] += x.x*x.x + x.y*x.y + x.z*x.z + x.w*x.w;
    r[1] += y.x*y.x + y.y*y.y + y.z*y.z + y.w*y.w;
    r[2] += z.x*z.x + z.y*z.y + z.z*z.z + z.w*z.w;
    r[3] += x.x*y.x + x.y*y.y + x.z*y.z + x.w*y.w;
    r[4] += x.x*z.x + x.y*z.y + x.z*z.z + x.w*z.w;
    r[5] += y.x*z.x + y.y*z.y + y.z*z.z + y.w*z.w;
  }
  __shared__ float lds[4][6];
  const int lane = tid & 63, wv = tid >> 6;
#pragma unroll
  for (int i = 0; i < 6; ++i) r[i] = wave_red(r[i]);
  if (lane == 0) {
#pragma unroll
    for (int i = 0; i < 6; ++i) lds[wv][i] = r[i];
  }
  __syncthreads();
  if (tid == 0) {
#pragma unroll
    for (int i = 0; i < 6; ++i)
      r[i] = lds[0][i] + lds[1][i] + lds[2][i] + lds[3][i];
    const float n0 = fmaxf(sqrtf(r[0]), 1e-12f);
    const float n1 = fmaxf(sqrtf(r[1]), 1e-12f);
    const float n2 = fmaxf(sqrtf(r[2]), 1e-12f);
    g_gram[0] = 1.f / n0;
    g_gram[1] = 1.f / n1;
    g_gram[2] = 1.f / n2;
    g_gram[3] = r[0] / (n0 * n0);
    g_gram[4] = r[1] / (n1 * n1);
    g_gram[5] = r[2] / (n2 * n2);
    g_gram[6] = r[3] / (n0 * n1);
    g_gram[7] = r[4] / (n0 * n2);
    g_gram[8] = r[5] / (n1 * n2);
  }
}

__global__ __launch_bounds__(TPB, 4) void fused_kernel(
    const float* __restrict__ h0,
    const float* __restrict__ an0, const float* __restrict__ an1,
    const float* __restrict__ an2, float* __restrict__ out) {
  const int tid = threadIdx.x;
  const int lane = tid & 63;
  const int wv = tid >> 6;
  const int b = blockIdx.x * WPB + wv;            // this wave's row

  // ---- stage anchors into LDS (48KB), once per block ----
  __shared__ float sa0[DIM], sa1[DIM], sa2[DIM];
#pragma unroll
  for (int j = 0; j < DIM / (TPB * 4); ++j) {     // 2 float4 per thread/anchor
    const int idx = (tid + j * TPB) * 4;
    *(float4*)(sa0 + idx) = *(const float4*)(an0 + idx);
    *(float4*)(sa1 + idx) = *(const float4*)(an1 + idx);
    *(float4*)(sa2 + idx) = *(const float4*)(an2 + idx);
  }
  __syncthreads();  // only barrier; LDS is read-only below, waves drift free

  // ---- pass 1a: ALL h-loads issued back-to-back (one latency exposure) ----
  const float* hrow = h0 + (size_t)b * DIM;
  float4 hv[FPW];
#pragma unroll
  for (int j = 0; j < FPW; ++j)
    hv[j] = *(const float4*)(hrow + (j * 64 + lane) * 4);

  // ---- pass 1b: dots; LDS reads batched CHUNK-deep before consumption ----
  float r0 = 0.f, r1 = 0.f, r2 = 0.f, r3 = 0.f;
#pragma unroll
  for (int jc = 0; jc < FPW; jc += CHUNK) {
    float4 xs[CHUNK], ys[CHUNK], zs[CHUNK];
#pragma unroll
    for (int u = 0; u < CHUNK; ++u) {
      const int idx = ((jc + u) * 64 + lane) * 4;
      xs[u] = *(const float4*)(sa0 + idx);
      ys[u] = *(const float4*)(sa1 + idx);
      zs[u] = *(const float4*)(sa2 + idx);
    }
#pragma unroll
    for (int u = 0; u < CHUNK; ++u) {
      const float4 h = hv[jc + u];
      r0 += h.x*h.x + h.y*h.y + h.z*h.z + h.w*h.w;
      r1 += h.x*xs[u].x + h.y*xs[u].y + h.z*xs[u].z + h.w*xs[u].w;
      r2 += h.x*ys[u].x + h.y*ys[u].y + h.z*ys[u].z + h.w*ys[u].w;
      r3 += h.x*zs[u].x + h.y*zs[u].y + h.z*zs[u].z + h.w*zs[u].w;
    }
  }

  // ---- wave-local butterfly reduce: all lanes hold the sums; no LDS ----
  float s  = wave_allred(r0);
  float d0 = wave_allred(r1);
  float d1 = wave_allred(r2);
  float d2 = wave_allred(r3);

  const float rn0 = g_gram[0], rn1 = g_gram[1], rn2 = g_gram[2];
  const float G00 = g_gram[3], G11 = g_gram[4], G22 = g_gram[5];
  const float G01 = g_gram[6], G02 = g_gram[7], G12 = g_gram[8];
  d0 *= rn0; d1 *= rn1; d2 *= rn2;

  float A = 1.f, B0 = 0.f, B1 = 0.f, B2 = 0.f;
  float* tr_al = out + OFF_ALIGN + (size_t)b * 3;
  float* tr_dv = out + OFF_DIV   + (size_t)b * 3;
  float* tr_tn = out + OFF_TENS  + (size_t)b * 3;

  // ---- recurrence: redundant per-lane; division-free native math ----
#pragma unroll
  for (int l = 0; l < NLAYERS; ++l) {
    const float rhn = frsq(fmaxf(s, 1e-24f));
    const float al0 = d0 * rhn, al1 = d1 * rhn, al2 = d2 * rhn;
    const float dv0 = 1.f - al0, dv1 = 1.f - al1, dv2 = 1.f - al2;
    const float rr0 = frsq(fmaxf(s - 2.f*d0 + G00, 1e-24f));
    const float rr1 = frsq(fmaxf(s - 2.f*d1 + G11, 1e-24f));
    const float rr2 = frsq(fmaxf(s - 2.f*d2 + G22, 1e-24f));
    const float c0 = 0.10f * dv0 * rr0;
    const float c1 = 0.10f * dv1 * rr1;
    const float c2 = 0.05f * dv2 * rr2;
    if (lane == 0) {
      const size_t o = (size_t)l * (BATCH * 3);
      tr_al[o+0] = al0; tr_al[o+1] = al1; tr_al[o+2] = al2;
      tr_dv[o+0] = dv0; tr_dv[o+1] = dv1; tr_dv[o+2] = dv2;
      tr_tn[o+0] = fmaxf(dv0, 0.f); tr_tn[o+1] = fmaxf(dv1, 0.f);
      tr_tn[o+2] = fmaxf(dv2, 0.f);
    }
    const float a = 1.f - (c0 + c1 + c2);
    const float dn0 = a*d0 + c0*G00 + c1*G01 + c2*G02;
    const float dn1 = a*d1 + c0*G01 + c1*G11 + c2*G12;
    const float dn2 = a*d2 + c0*G02 + c1*G12 + c2*G22;
    float sn = a*a*s + 2.f*a*(c0*d0 + c1*d1 + c2*d2)
             + c0*c0*G00 + c1*c1*G11 + c2*c2*G22
             + 2.f*(c0*c1*G01 + c0*c2*G02 + c1*c2*G12);
    A = a * A;
    B0 = a*B0 + c0; B1 = a*B1 + c1; B2 = a*B2 + c2;
    s = sn; d0 = dn0; d1 = dn1; d2 = dn2;
    const float hn2 = fsq(s);
    if (hn2 > 10.0f) {                              // wave-uniform branch
      const float sc = 10.0f * frcp(hn2 + 1e-8f);
      A *= sc; B0 *= sc; B1 *= sc; B2 *= sc;
      d0 *= sc; d1 *= sc; d2 *= sc;
      s *= sc * sc;
    }
  }
  const float w0 = B0 * rn0, w1 = B1 * rn1, w2 = B2 * rn2;

  // ---- pass 2: LDS reads batched; stores fire-and-forget ----
  float* orow = out + (size_t)b * DIM;
#pragma unroll
  for (int jc = 0; jc < FPW; jc += CHUNK) {
    float4 xs[CHUNK], ys[CHUNK], zs[CHUNK];
#pragma unroll
    for (int u = 0; u < CHUNK; ++u) {
      const int idx = ((jc + u) * 64 + lane) * 4;
      xs[u] = *(const float4*)(sa0 + idx);
      ys[u] = *(const float4*)(sa1 + idx);
      zs[u] = *(const float4*)(sa2 + idx);
    }
#pragma unroll
    for (int u = 0; u < CHUNK; ++u) {
      const int idx = ((jc + u) * 64 + lane) * 4;
      const float4 h = hv[jc + u];
      float4 o;
      o.x = A * h.x + w0 * xs[u].x + w1 * ys[u].x + w2 * zs[u].x;
      o.y = A * h.y + w0 * xs[u].y + w1 * ys[u].y + w2 * zs[u].y;
      o.z = A * h.z + w0 * xs[u].z + w1 * ys[u].z + w2 * zs[u].z;
      o.w = A * h.w + w0 * xs[u].w + w1 * ys[u].w + w2 * zs[u].w;
      *(float4*)(orow + idx) = o;
    }
  }
}

extern "C" void kernel_launch(void* const* d_in, const int* in_sizes, int n_in,
                              void* d_out, int out_size, void* d_ws, size_t ws_size,
                              hipStream_t stream) {
  const float* h0  = (const float*)d_in[0];
  const float* an0 = (const float*)d_in[1];
  const float* an1 = (const float*)d_in[2];
  const float* an2 = (const float*)d_in[3];
  float* out = (float*)d_out;
  (void)d_ws; (void)ws_size;
  gram_kernel<<<1, GTPB, 0, stream>>>(an0, an1, an2);
  fused_kernel<<<GRID, TPB, 0, stream>>>(h0, an0, an1, an2, out);
}